// Round 8
// baseline (159.779 us; speedup 1.0000x reference)
//
#include <hip/hip_runtime.h>
#include <hip/hip_bf16.h>

#define BB 8
#define SS 1024
#define HH 16
#define DD 64
#define DIMM 1024
#define NUNITS (BB * HH)          // 128 independent (b,h) units
#define UNIT_ELEMS (SS * DD)      // 65536 elems per array per unit

typedef __attribute__((ext_vector_type(8))) short short8;
typedef __attribute__((ext_vector_type(4))) float f32x4;

#if __has_builtin(__builtin_amdgcn_exp2f)
#define EXP2F(x) __builtin_amdgcn_exp2f(x)
#else
#define EXP2F(x) exp2f(x)
#endif
#if __has_builtin(__builtin_amdgcn_rcpf)
#define RCPF(x) __builtin_amdgcn_rcpf(x)
#else
#define RCPF(x) (1.0f / (x))
#endif

// RNE float->bf16, finite inputs only
__device__ inline short f2b(float f) {
    unsigned u = __float_as_uint(f);
    u = (u + 0x7FFFu + ((u >> 16) & 1u)) >> 16;
    return (short)u;
}
// pack two fp32 -> bf16x2 (lo, hi), RNE
__device__ inline unsigned pk2(float lo, float hi) {
    unsigned a = __float_as_uint(lo), b = __float_as_uint(hi);
    a = (a + 0x7FFFu + ((a >> 16) & 1u)) >> 16;
    b = (b + 0x7FFFu + ((b >> 16) & 1u)) & 0xFFFF0000u;
    return a | b;
}
// two float4 -> short8 (bf16 RNE)
__device__ inline short8 pack8(float4 a, float4 b) {
    short8 o;
    o[0] = f2b(a.x); o[1] = f2b(a.y); o[2] = f2b(a.z); o[3] = f2b(a.w);
    o[4] = f2b(b.x); o[5] = f2b(b.y); o[6] = f2b(b.z); o[7] = f2b(b.w);
    return o;
}

// ---------------- Kernel 1: QKV projection v3 ----------------
// grid = nu*4 blocks (4 s-tiles each), 256 thr. W held as register fragments
// (loaded once, L2-hot). Per tile: stage x, 24 MFMAs in transpose orientation,
// pk2-packed b64 LDS pivots, coalesced short8 flush. 3 barriers/tile.
// Bias: only bq applied (bk cancels in softmax exactly; bv folded into attn).
// Writes: Q,K natural [ul][s][d] (Q pre-scaled 0.125), V transposed [ul][d][s].
__global__ __launch_bounds__(256) void qkv_proj(
    const float* __restrict__ x, const float* __restrict__ Wq,
    const float* __restrict__ Wk, const float* __restrict__ Wv,
    const float* __restrict__ bqp,
    short* __restrict__ Qo, short* __restrict__ Ko, short* __restrict__ Vto,
    int unit0)
{
    __shared__ alignas(16) short xs[64][72];
    __shared__ alignas(16) short qtm[64][72];
    __shared__ alignas(16) short ktm[64][72];
    __shared__ alignas(16) short vtm[64][72];

    const int t = threadIdx.x;
    const int bid = blockIdx.x;
    const int stg = bid & 3;
    const int ul = bid >> 2;
    const int unit = unit0 + ul;
    const int h = unit & 15;
    const int b = unit >> 4;

    const int lane = t & 63, w = t >> 6;
    const int l15 = lane & 15, quad = lane >> 4;

    // W register fragments: lane holds W[et*16+l15][c*32 + quad*8 + j] (bf16)
    short8 wq[4][2], wk[4][2], wv[4][2];
    {
        const size_t wb = (size_t)h * DD * DD + (size_t)l15 * DD + quad * 8;
        for (int et = 0; et < 4; ++et)
            for (int c = 0; c < 2; ++c) {
                size_t off = wb + (size_t)et * 16 * DD + c * 32;
                wq[et][c] = pack8(*reinterpret_cast<const float4*>(Wq + off),
                                  *reinterpret_cast<const float4*>(Wq + off + 4));
                wk[et][c] = pack8(*reinterpret_cast<const float4*>(Wk + off),
                                  *reinterpret_cast<const float4*>(Wk + off + 4));
                wv[et][c] = pack8(*reinterpret_cast<const float4*>(Wv + off),
                                  *reinterpret_cast<const float4*>(Wv + off + 4));
            }
    }

    for (int st2 = 0; st2 < 4; ++st2) {
        const int s0 = (stg * 4 + st2) * 64;
        if (st2) __syncthreads();          // prev tile's xs reads + flush reads done
        // stage x (fp32 -> bf16)
        for (int i = 0; i < 4; ++i) {
            int g = t + i * 256;
            int r = g >> 4, c = (g & 15) * 4;
            float4 xv = *reinterpret_cast<const float4*>(
                x + ((size_t)(b * SS + s0 + r)) * DIMM + h * DD + c);
            short4 sv; sv.x = f2b(xv.x); sv.y = f2b(xv.y); sv.z = f2b(xv.z); sv.w = f2b(xv.w);
            *reinterpret_cast<short4*>(&xs[r][c]) = sv;
        }
        __syncthreads();

        short8 xa0 = *reinterpret_cast<const short8*>(&xs[w * 16 + l15][quad * 8]);
        short8 xa1 = *reinterpret_cast<const short8*>(&xs[w * 16 + l15][32 + quad * 8]);

        for (int et = 0; et < 4; ++et) {
            // Q^T, K^T: C[e][srow] = mfma(A=W-frag, B=x-frag)
            f32x4 aq = {0.f, 0.f, 0.f, 0.f};
            aq = __builtin_amdgcn_mfma_f32_16x16x32_bf16(wq[et][0], xa0, aq, 0, 0, 0);
            aq = __builtin_amdgcn_mfma_f32_16x16x32_bf16(wq[et][1], xa1, aq, 0, 0, 0);
            f32x4 ak = {0.f, 0.f, 0.f, 0.f};
            ak = __builtin_amdgcn_mfma_f32_16x16x32_bf16(wk[et][0], xa0, ak, 0, 0, 0);
            ak = __builtin_amdgcn_mfma_f32_16x16x32_bf16(wk[et][1], xa1, ak, 0, 0, 0);
            // V: C[srow][e] = mfma(A=x-frag, B=W-frag)
            f32x4 av = {0.f, 0.f, 0.f, 0.f};
            av = __builtin_amdgcn_mfma_f32_16x16x32_bf16(xa0, wv[et][0], av, 0, 0, 0);
            av = __builtin_amdgcn_mfma_f32_16x16x32_bf16(xa1, wv[et][1], av, 0, 0, 0);

            float4 bq4 = *reinterpret_cast<const float4*>(bqp + h * DD + et * 16 + quad * 4);
            uint2 pq;
            pq.x = pk2((aq[0] + bq4.x) * 0.125f, (aq[1] + bq4.y) * 0.125f);
            pq.y = pk2((aq[2] + bq4.z) * 0.125f, (aq[3] + bq4.w) * 0.125f);
            *reinterpret_cast<uint2*>(&qtm[w * 16 + l15][et * 16 + quad * 4]) = pq;
            uint2 pkk; pkk.x = pk2(ak[0], ak[1]); pkk.y = pk2(ak[2], ak[3]);
            *reinterpret_cast<uint2*>(&ktm[w * 16 + l15][et * 16 + quad * 4]) = pkk;
            uint2 pv; pv.x = pk2(av[0], av[1]); pv.y = pk2(av[2], av[3]);
            *reinterpret_cast<uint2*>(&vtm[et * 16 + l15][w * 16 + quad * 4]) = pv;
        }
        __syncthreads();
        // coalesced flush
        for (int i = 0; i < 2; ++i) {
            int g = t + i * 256;
            int row = g >> 3, col = (g & 7) * 8;
            *reinterpret_cast<short8*>(Qo + ((size_t)ul * SS + s0 + row) * DD + col) =
                *reinterpret_cast<const short8*>(&qtm[row][col]);
            *reinterpret_cast<short8*>(Ko + ((size_t)ul * SS + s0 + row) * DD + col) =
                *reinterpret_cast<const short8*>(&ktm[row][col]);
            *reinterpret_cast<short8*>(Vto + ((size_t)ul * DD + row) * SS + s0 + col) =
                *reinterpret_cast<const short8*>(&vtm[row][col]);
        }
    }
}

// ---------------- Kernel 2: flash attention (unchanged structure + bv epilogue) ----------------
__global__ __launch_bounds__(256, 4) void attn(
    const short* __restrict__ Q, const short* __restrict__ K,
    const short* __restrict__ Vt, const float* __restrict__ bvp,
    float* __restrict__ out, int unit0, int nu)
{
    __shared__ alignas(16) short ks[64][72];    // K tile [key][d]
    __shared__ alignas(16) short vts[64][72];   // Vt tile [d][key]
    __shared__ alignas(16) short ps[4][32][72]; // per-wave P [strip*16+q][key]

    const int t = threadIdx.x;
    const int bid = blockIdx.x;
    int ul, qt;
    if (nu == NUNITS) {   // XCD-aware swizzle
        int xslot = bid & 7;
        int j = bid >> 3;
        ul = xslot * 16 + (j & 15);
        qt = j >> 4;
    } else {
        ul = bid >> 3;
        qt = bid & 7;
    }
    const int unit = unit0 + ul;
    const int h = unit & 15;
    const int b = unit >> 4;
    const int q0 = qt * 128;
    const int lane = t & 63, w = t >> 6;
    const int l15 = lane & 15, quad = lane >> 4;

    short8 qa[2][2];
    for (int s = 0; s < 2; ++s) {
        const short* qp = Q + ((size_t)ul * SS + q0 + s * 64 + w * 16 + l15) * DD;
        qa[s][0] = *reinterpret_cast<const short8*>(qp + quad * 8);
        qa[s][1] = *reinterpret_cast<const short8*>(qp + 32 + quad * 8);
    }

    short8 ones;
    for (int j = 0; j < 8; ++j) ones[j] = (short)0x3F80;  // bf16 1.0

    f32x4 o[8];
    f32x4 lacc[2];
    for (int i = 0; i < 8; ++i) o[i] = (f32x4){0.f, 0.f, 0.f, 0.f};
    lacc[0] = (f32x4){0.f, 0.f, 0.f, 0.f};
    lacc[1] = (f32x4){0.f, 0.f, 0.f, 0.f};

    const int srow_ = t >> 3, scol = (t & 7) * 8;

    const short* kg = K + (size_t)ul * UNIT_ELEMS + srow_ * DD + scol;
    const short* vg = Vt + (size_t)ul * UNIT_ELEMS + srow_ * SS + scol;
    char* ksw = (char*)&ks[srow_][scol];
    char* vtw = (char*)&vts[srow_][scol];
    const char* kbp = (const char*)&ks[l15][quad * 8];
    const char* vbp = (const char*)&vts[l15][quad * 8];
    const char* pap = (const char*)&ps[w][l15][quad * 8];
    char* psw = (char*)&ps[w][l15][quad * 4];

    const float L2E = 1.44269504f;
    const float MBIAS = 11.5415603f;   // 8*log2(e): p = exp(s-8)

    for (int kt = 0; kt < 16; ++kt) {
        __syncthreads();
        *reinterpret_cast<short8*>(ksw) = *reinterpret_cast<const short8*>(kg);
        *reinterpret_cast<short8*>(ksw + 32 * 144) = *reinterpret_cast<const short8*>(kg + 32 * DD);
        *reinterpret_cast<short8*>(vtw) = *reinterpret_cast<const short8*>(vg);
        *reinterpret_cast<short8*>(vtw + 32 * 144) = *reinterpret_cast<const short8*>(vg + 32 * SS);
        kg += 64 * DD;
        vg += 64;
        __syncthreads();

        for (int n = 0; n < 4; ++n) {
            short8 kb0 = *reinterpret_cast<const short8*>(kbp + n * 2304);
            short8 kb1 = *reinterpret_cast<const short8*>(kbp + n * 2304 + 64);
            for (int s = 0; s < 2; ++s) {
                f32x4 a = {0.f, 0.f, 0.f, 0.f};
                a = __builtin_amdgcn_mfma_f32_16x16x32_bf16(kb0, qa[s][0], a, 0, 0, 0);
                a = __builtin_amdgcn_mfma_f32_16x16x32_bf16(kb1, qa[s][1], a, 0, 0, 0);
                float p0 = EXP2F(fmaf(a[0], L2E, -MBIAS));
                float p1 = EXP2F(fmaf(a[1], L2E, -MBIAS));
                float p2 = EXP2F(fmaf(a[2], L2E, -MBIAS));
                float p3 = EXP2F(fmaf(a[3], L2E, -MBIAS));
                uint2 pk; pk.x = pk2(p0, p1); pk.y = pk2(p2, p3);
                *reinterpret_cast<uint2*>(psw + s * 2304 + n * 32) = pk;
            }
        }

        short8 pa[2][2];
        for (int s = 0; s < 2; ++s) {
            pa[s][0] = *reinterpret_cast<const short8*>(pap + s * 2304);
            pa[s][1] = *reinterpret_cast<const short8*>(pap + s * 2304 + 64);
            lacc[s] = __builtin_amdgcn_mfma_f32_16x16x32_bf16(pa[s][0], ones, lacc[s], 0, 0, 0);
            lacc[s] = __builtin_amdgcn_mfma_f32_16x16x32_bf16(pa[s][1], ones, lacc[s], 0, 0, 0);
        }
        for (int dt = 0; dt < 4; ++dt) {
            short8 vb0 = *reinterpret_cast<const short8*>(vbp + dt * 2304);
            short8 vb1 = *reinterpret_cast<const short8*>(vbp + dt * 2304 + 64);
            for (int s = 0; s < 2; ++s) {
                o[s * 4 + dt] = __builtin_amdgcn_mfma_f32_16x16x32_bf16(pa[s][0], vb0, o[s * 4 + dt], 0, 0, 0);
                o[s * 4 + dt] = __builtin_amdgcn_mfma_f32_16x16x32_bf16(pa[s][1], vb1, o[s * 4 + dt], 0, 0, 0);
            }
        }
    }

    // epilogue: out = O * rcp(l) + bv  (bv folded here: P(V0+bv) = P·V0 + bv·l, exact)
    float bvv[4];
    for (int dt = 0; dt < 4; ++dt) bvv[dt] = bvp[h * DD + dt * 16 + l15];
    float* outp = out + ((size_t)b * SS + q0 + w * 16 + quad * 4) * DIMM + h * DD + l15;
    for (int s = 0; s < 2; ++s)
        for (int r = 0; r < 4; ++r) {
            float rin = RCPF(lacc[s][r]);
            for (int dt = 0; dt < 4; ++dt)
                outp[(size_t)(s * 64 + r) * DIMM + dt * 16] = fmaf(o[s * 4 + dt][r], rin, bvv[dt]);
        }
}

extern "C" void kernel_launch(void* const* d_in, const int* in_sizes, int n_in,
                              void* d_out, int out_size, void* d_ws, size_t ws_size,
                              hipStream_t stream) {
    const float* x   = (const float*)d_in[0];
    const float* Wq  = (const float*)d_in[1];
    const float* Wk  = (const float*)d_in[2];
    const float* Wv  = (const float*)d_in[3];
    const float* bqp = (const float*)d_in[4];
    const float* bvp = (const float*)d_in[6];
    float* out = (float*)d_out;

    const size_t unit_bytes = 3ULL * UNIT_ELEMS * sizeof(short);  // 384 KB / unit
    int U = (int)(ws_size / unit_bytes);
    if (U < 1) U = 1;
    if (U > NUNITS) U = NUNITS;

    short* Qw  = (short*)d_ws;
    short* Kw  = Qw + (size_t)U * UNIT_ELEMS;
    short* Vtw = Kw + (size_t)U * UNIT_ELEMS;

    for (int u0 = 0; u0 < NUNITS; u0 += U) {
        int nu = NUNITS - u0 < U ? NUNITS - u0 : U;
        qkv_proj<<<dim3(nu * 4), dim3(256), 0, stream>>>(
            x, Wq, Wk, Wv, bqp, Qw, Kw, Vtw, u0);
        attn<<<dim3(nu * 8), dim3(256), 0, stream>>>(Qw, Kw, Vtw, bvp, out, u0, nu);
    }
}